// Round 5
// baseline (1699.144 us; speedup 1.0000x reference)
//
#include <hip/hip_runtime.h>
#include <hip/hip_bf16.h>

#define CIN 256
#define COUT 64
#define WPAD 264       // padded K stride for transposed W in LDS
#define BSHIFT 8       // nodes per bucket = 256
#define NPB 256        // nodes per bucket
#define NWG 256        // workgroups for binning passes

typedef __attribute__((ext_vector_type(8))) short short8;
typedef __attribute__((ext_vector_type(4))) float floatx4;

static __device__ __forceinline__ unsigned int fbits(float f) {
    return __builtin_bit_cast(unsigned int, f);
}
static __device__ __forceinline__ float bbits(unsigned int u) {
    return __builtin_bit_cast(float, u);
}
// RTN fp32->bf16 (used only in gemm epilogue, where rounding matters most)
static __device__ __forceinline__ unsigned short f2bf(float f) {
    unsigned u = fbits(f);
    return (unsigned short)((u + 0x7FFFu + ((u >> 16) & 1u)) >> 16);
}
static __device__ __forceinline__ float bf2f(unsigned short h) {
    return bbits(((unsigned)h) << 16);
}

// truncation-split of 8 fp32 (two float4) into bf16 hi/lo short8 fragments.
// hi = top-16-bits(f); lo = trunc16(f - hi). Representation error ~2^-16 rel.
union U8 { short8 s; unsigned int u[4]; };
static __device__ __forceinline__ void split8(floatx4 a0, floatx4 a1,
                                              short8& hi, short8& lo) {
    float f[8] = {a0[0], a0[1], a0[2], a0[3], a1[0], a1[1], a1[2], a1[3]};
    U8 H, L;
#pragma unroll
    for (int j = 0; j < 4; ++j) {
        unsigned u0 = fbits(f[2 * j]);
        unsigned u1 = fbits(f[2 * j + 1]);
        // dst = [u0.hi16 (low half), u1.hi16 (high half)] in one v_perm_b32
        H.u[j] = __builtin_amdgcn_perm(u1, u0, 0x07060302u);
        float r0 = f[2 * j] - bbits(u0 & 0xFFFF0000u);
        float r1 = f[2 * j + 1] - bbits(u1 & 0xFFFF0000u);
        L.u[j] = __builtin_amdgcn_perm(fbits(r1), fbits(r0), 0x07060302u);
    }
    hi = H.s;
    lo = L.s;
}

// ---------------- K1: per-workgroup bucket histogram + zero deg ----------------
__global__ __launch_bounds__(256) void k1_bucket_hist(const int* __restrict__ dst,
                                                      int* __restrict__ H,
                                                      int* __restrict__ deg,
                                                      int E, int chunk, int nbuck, int N) {
    // zero global degree counters (k3 accumulates into them later)
    for (int i = blockIdx.x * 256 + threadIdx.x; i < N; i += 256 * NWG) deg[i] = 0;

    __shared__ int cnt[512];
    for (int i = threadIdx.x; i < nbuck; i += 256) cnt[i] = 0;
    __syncthreads();
    const int g = blockIdx.x;
    const int e0 = g * chunk;
    const int e1 = min(E, e0 + chunk);
    for (int e = e0 + threadIdx.x; e < e1; e += 256)
        atomicAdd(&cnt[dst[e] >> BSHIFT], 1);
    __syncthreads();
    for (int i = threadIdx.x; i < nbuck; i += 256) H[i * NWG + g] = cnt[i];
}

// ---------------- 2-level exclusive scan (over H, bucket-major) ----------------
__global__ __launch_bounds__(1024) void scan_a(const int* __restrict__ in,
                                               int* __restrict__ out,
                                               int* __restrict__ bsums, int n) {
    __shared__ int sm[1024];
    int i = blockIdx.x * 1024 + threadIdx.x;
    int v = (i < n) ? in[i] : 0;
    sm[threadIdx.x] = v;
    __syncthreads();
    for (int off = 1; off < 1024; off <<= 1) {
        int t = (threadIdx.x >= off) ? sm[threadIdx.x - off] : 0;
        __syncthreads();
        sm[threadIdx.x] += t;
        __syncthreads();
    }
    if (i < n) out[i] = sm[threadIdx.x] - v;  // exclusive (pre block offset)
    if (threadIdx.x == 1023) bsums[blockIdx.x] = sm[1023];
}

__global__ __launch_bounds__(1024) void scan_b(const int* __restrict__ bsums,
                                               int* __restrict__ boffs, int NB) {
    __shared__ int sm[1024];
    int v = (threadIdx.x < NB) ? bsums[threadIdx.x] : 0;
    sm[threadIdx.x] = v;
    __syncthreads();
    for (int off = 1; off < 1024; off <<= 1) {
        int t = (threadIdx.x >= off) ? sm[threadIdx.x - off] : 0;
        __syncthreads();
        sm[threadIdx.x] += t;
        __syncthreads();
    }
    if (threadIdx.x < NB) boffs[threadIdx.x] = sm[threadIdx.x] - v;
}

// ---------------- K3: binned append of packed (dstlow8<<17 | src17) + degree ----------------
__global__ __launch_bounds__(256) void k3_bin(const int* __restrict__ src,
                                              const int* __restrict__ dst,
                                              const int* __restrict__ O,
                                              const int* __restrict__ boffs,
                                              int* __restrict__ packed,
                                              int* __restrict__ deg,
                                              int E, int chunk, int nbuck) {
    __shared__ int cur[512];
    const int g = blockIdx.x;
    for (int i = threadIdx.x; i < nbuck; i += 256) {
        const int fi = i * NWG + g;
        cur[i] = O[fi] + boffs[fi >> 10];
    }
    __syncthreads();
    const int e0 = g * chunk;
    const int e1 = min(E, e0 + chunk);
    for (int e = e0 + threadIdx.x; e < e1; e += 256) {
        const int d = dst[e];
        const int b = d >> BSHIFT;
        const int pos = atomicAdd(&cur[b], 1);
        packed[pos] = ((d & (NPB - 1)) << 17) | src[e];
        atomicAdd(&deg[d], 1);  // fire-and-forget, no return
    }
}

// ---------------- dinv = rsqrt(deg + 1) ----------------
__global__ void k_dinv(const int* __restrict__ deg, float* __restrict__ dinv, int N) {
    int i = blockIdx.x * blockDim.x + threadIdx.x;
    if (i < N) dinv[i] = rsqrtf((float)(deg[i] + 1));
}

// ---------------- h2 = bf16((x @ W) * dinv[row])  via bf16x3 MFMA ----------------
// 512 threads = 8 waves; each wave computes 32 rows (two 16-row tiles) x 64 cols.
__global__ __launch_bounds__(512) void gemm_mfma_kernel(const float* __restrict__ x,
                                                        const float* __restrict__ W,
                                                        const float* __restrict__ dinv,
                                                        unsigned short* __restrict__ h2,
                                                        int N) {
    __shared__ unsigned short Whi[COUT * WPAD];
    __shared__ unsigned short Wlo[COUT * WPAD];
    for (int i = threadIdx.x; i < CIN * COUT; i += 512) {
        int k = i >> 6, c = i & 63;
        float w = W[i];
        unsigned u = fbits(w);
        unsigned short h = (unsigned short)(u >> 16);  // trunc split
        float r = w - bbits(u & 0xFFFF0000u);
        Whi[c * WPAD + k] = h;
        Wlo[c * WPAD + k] = (unsigned short)(fbits(r) >> 16);
    }
    __syncthreads();

    const int lane = threadIdx.x & 63;
    const int wave = threadIdx.x >> 6;
    const int m = lane & 15;
    const int q = lane >> 4;
    const int row0 = blockIdx.x * 256 + wave * 32;

    int ar0 = row0 + m;
    int ar1 = row0 + 16 + m;
    if (ar0 >= N) ar0 = N - 1;  // clamp; stores are guarded
    if (ar1 >= N) ar1 = N - 1;
    const float* __restrict__ xr0 = x + (size_t)ar0 * CIN + q * 8;
    const float* __restrict__ xr1 = x + (size_t)ar1 * CIN + q * 8;

    floatx4 acc0[4] = {floatx4{0,0,0,0}, floatx4{0,0,0,0}, floatx4{0,0,0,0}, floatx4{0,0,0,0}};
    floatx4 acc1[4] = {floatx4{0,0,0,0}, floatx4{0,0,0,0}, floatx4{0,0,0,0}, floatx4{0,0,0,0}};

#pragma unroll
    for (int kc = 0; kc < 8; ++kc) {
        floatx4 a00 = *(const floatx4*)(xr0 + kc * 32);
        floatx4 a01 = *(const floatx4*)(xr0 + kc * 32 + 4);
        floatx4 a10 = *(const floatx4*)(xr1 + kc * 32);
        floatx4 a11 = *(const floatx4*)(xr1 + kc * 32 + 4);
        short8 ahi0, alo0, ahi1, alo1;
        split8(a00, a01, ahi0, alo0);
        split8(a10, a11, ahi1, alo1);
        const int kb = kc * 32 + q * 8;
#pragma unroll
        for (int ct = 0; ct < 4; ++ct) {
            const int c = ct * 16 + m;
            short8 bhi = *(const short8*)&Whi[c * WPAD + kb];
            short8 blo = *(const short8*)&Wlo[c * WPAD + kb];
            acc0[ct] = __builtin_amdgcn_mfma_f32_16x16x32_bf16(ahi0, bhi, acc0[ct], 0, 0, 0);
            acc0[ct] = __builtin_amdgcn_mfma_f32_16x16x32_bf16(ahi0, blo, acc0[ct], 0, 0, 0);
            acc0[ct] = __builtin_amdgcn_mfma_f32_16x16x32_bf16(alo0, bhi, acc0[ct], 0, 0, 0);
            acc1[ct] = __builtin_amdgcn_mfma_f32_16x16x32_bf16(ahi1, bhi, acc1[ct], 0, 0, 0);
            acc1[ct] = __builtin_amdgcn_mfma_f32_16x16x32_bf16(ahi1, blo, acc1[ct], 0, 0, 0);
            acc1[ct] = __builtin_amdgcn_mfma_f32_16x16x32_bf16(alo1, bhi, acc1[ct], 0, 0, 0);
        }
    }

    // C/D layout: col = lane&15 (= m), row = q*4 + reg
#pragma unroll
    for (int t = 0; t < 2; ++t) {
#pragma unroll
        for (int r = 0; r < 4; ++r) {
            const int row = row0 + t * 16 + q * 4 + r;
            if (row < N) {
                const float dv = dinv[row];
                unsigned short* __restrict__ op = h2 + (size_t)row * COUT;
#pragma unroll
                for (int ct = 0; ct < 4; ++ct) {
                    float v = (t == 0) ? acc0[ct][r] : acc1[ct][r];
                    op[ct * 16 + m] = f2bf(v * dv);
                }
            }
        }
    }
}

// ---------------- K5: fused gather — per-bucket LDS fp32 accumulators ----------------
// One block (512 thr, 8 waves) per bucket. Edges consumed straight from packed;
// each edge: 64-lane 128B h2-row load + ds atomic add into acc[dl][lane].
__global__ __launch_bounds__(512) void k5_gather(const unsigned short* __restrict__ h2,
                                                 const int* __restrict__ O,
                                                 const int* __restrict__ boffs,
                                                 const int* __restrict__ packed,
                                                 const float* __restrict__ dinv,
                                                 const float* __restrict__ bias,
                                                 float* __restrict__ out,
                                                 int N, int E, int nbuck) {
    __shared__ float acc[NPB * COUT];  // 64 KB -> 2 blocks/CU
    for (int i = threadIdx.x; i < NPB * COUT / 4; i += 512)
        ((float4*)acc)[i] = float4{0.f, 0.f, 0.f, 0.f};

    const int b = blockIdx.x;
    const int ib = b * NWG;
    const int segbeg = O[ib] + boffs[ib >> 10];
    int segend = E;
    if (b + 1 < nbuck) {
        const int ie = (b + 1) * NWG;
        segend = O[ie] + boffs[ie >> 10];
    }
    const int n0 = b << BSHIFT;
    const int ncnt = min(N - n0, NPB);
    const int lane = threadIdx.x & 63;
    const int wv = threadIdx.x >> 6;
    const float bi = bias[lane];
    __syncthreads();

    // edge loop: wave-strided (stride 8), unroll 8 for MLP
    int e = segbeg + wv;
    const int end8 = segend - 56;
    for (; e < end8; e += 64) {
        int p0 = packed[e],      p1 = packed[e + 8],  p2 = packed[e + 16], p3 = packed[e + 24];
        int p4 = packed[e + 32], p5 = packed[e + 40], p6 = packed[e + 48], p7 = packed[e + 56];
        float v0 = bf2f(h2[(size_t)(p0 & 0x1FFFF) * COUT + lane]);
        float v1 = bf2f(h2[(size_t)(p1 & 0x1FFFF) * COUT + lane]);
        float v2 = bf2f(h2[(size_t)(p2 & 0x1FFFF) * COUT + lane]);
        float v3 = bf2f(h2[(size_t)(p3 & 0x1FFFF) * COUT + lane]);
        float v4 = bf2f(h2[(size_t)(p4 & 0x1FFFF) * COUT + lane]);
        float v5 = bf2f(h2[(size_t)(p5 & 0x1FFFF) * COUT + lane]);
        float v6 = bf2f(h2[(size_t)(p6 & 0x1FFFF) * COUT + lane]);
        float v7 = bf2f(h2[(size_t)(p7 & 0x1FFFF) * COUT + lane]);
        atomicAdd(&acc[(p0 >> 17) * COUT + lane], v0);
        atomicAdd(&acc[(p1 >> 17) * COUT + lane], v1);
        atomicAdd(&acc[(p2 >> 17) * COUT + lane], v2);
        atomicAdd(&acc[(p3 >> 17) * COUT + lane], v3);
        atomicAdd(&acc[(p4 >> 17) * COUT + lane], v4);
        atomicAdd(&acc[(p5 >> 17) * COUT + lane], v5);
        atomicAdd(&acc[(p6 >> 17) * COUT + lane], v6);
        atomicAdd(&acc[(p7 >> 17) * COUT + lane], v7);
    }
    for (; e < segend; e += 8) {
        int p = packed[e];
        float v = bf2f(h2[(size_t)(p & 0x1FFFF) * COUT + lane]);
        atomicAdd(&acc[(p >> 17) * COUT + lane], v);
    }
    __syncthreads();

    // epilogue: out[n] = dinv[n]*(acc[n] + h2[n]) + b   (self-loop = h2[n])
    for (int i = wv; i < ncnt; i += 8) {
        const int n = n0 + i;
        const float self = bf2f(h2[(size_t)n * COUT + lane]);
        out[(size_t)n * COUT + lane] = (acc[i * COUT + lane] + self) * dinv[n] + bi;
    }
}

// ---------------- launch ----------------
extern "C" void kernel_launch(void* const* d_in, const int* in_sizes, int n_in,
                              void* d_out, int out_size, void* d_ws, size_t ws_size,
                              hipStream_t stream) {
    const float* x = (const float*)d_in[0];
    const int* ei = (const int*)d_in[1];
    const float* W = (const float*)d_in[2];
    const float* b = (const float*)d_in[3];
    float* out = (float*)d_out;

    const int N = in_sizes[0] / CIN;
    const int E = in_sizes[1] / 2;
    const int* src = ei;
    const int* dst = ei + E;

    const int nbuck = (N + NPB - 1) >> BSHIFT;        // 391
    const int nH = nbuck * NWG;                        // 100096
    const int chunk = (E + NWG - 1) / NWG;             // 12500
    const int NBs = (nH + 1023) / 1024;                // 98

    // workspace layout (256 B aligned chunks)
    auto align_up = [](size_t v) { return (v + 255) & ~(size_t)255; };
    char* ws = (char*)d_ws;
    size_t off = 0;
    int* H = (int*)(ws + off);        off = align_up(off + (size_t)nH * 4);
    int* O = (int*)(ws + off);        off = align_up(off + (size_t)nH * 4);
    int* bsums = (int*)(ws + off);    off = align_up(off + (size_t)NBs * 4);
    int* boffs = (int*)(ws + off);    off = align_up(off + (size_t)NBs * 4);
    int* deg = (int*)(ws + off);      off = align_up(off + (size_t)N * 4);
    float* dinv = (float*)(ws + off); off = align_up(off + (size_t)N * 4);
    int* packed = (int*)(ws + off);   off = align_up(off + (size_t)E * 4);
    unsigned short* h2 = (unsigned short*)(ws + off);
    off = align_up(off + (size_t)N * COUT * 2);
    (void)ws_size;

    // 1. per-workgroup bucket histogram + zero deg
    k1_bucket_hist<<<NWG, 256, 0, stream>>>(dst, H, deg, E, chunk, nbuck, N);
    // 2-3. exclusive scan of H (bucket-major, wg-minor) -> private ranges O
    scan_a<<<NBs, 1024, 0, stream>>>(H, O, bsums, nH);
    scan_b<<<1, 1024, 0, stream>>>(bsums, boffs, NBs);
    // 4. binned append of packed edges + global degree atomics
    k3_bin<<<NWG, 256, 0, stream>>>(src, dst, O, boffs, packed, deg, E, chunk, nbuck);
    // 5. dinv
    k_dinv<<<(N + 255) / 256, 256, 0, stream>>>(deg, dinv, N);
    // 6. projection h2 = bf16((x@W)*dinv) via bf16x3 MFMA, 32 rows/wave
    gemm_mfma_kernel<<<(N + 255) / 256, 512, 0, stream>>>(x, W, dinv, h2, N);
    // 7. fused gather: per-bucket LDS accumulation straight from packed
    k5_gather<<<nbuck, 512, 0, stream>>>(h2, O, boffs, packed, dinv, b, out, N, E, nbuck);
}

// Round 6
// 369.849 us; speedup vs baseline: 4.5942x; 4.5942x over previous
//
#include <hip/hip_runtime.h>
#include <hip/hip_bf16.h>

#define CIN 256
#define COUT 64
#define WPAD 264       // padded K stride for transposed W in LDS
#define BSHIFT 8       // nodes per bucket = 256
#define NPB 256        // nodes per bucket
#define NWG 256        // workgroups for binning passes

typedef __attribute__((ext_vector_type(8))) short short8;
typedef __attribute__((ext_vector_type(4))) float floatx4;

static __device__ __forceinline__ unsigned int fbits(float f) {
    return __builtin_bit_cast(unsigned int, f);
}
static __device__ __forceinline__ float bbits(unsigned int u) {
    return __builtin_bit_cast(float, u);
}
// RTN fp32->bf16 (gemm epilogue only)
static __device__ __forceinline__ unsigned short f2bf(float f) {
    unsigned u = fbits(f);
    return (unsigned short)((u + 0x7FFFu + ((u >> 16) & 1u)) >> 16);
}
static __device__ __forceinline__ float bf2f(unsigned short h) {
    return bbits(((unsigned)h) << 16);
}

// truncation-split of 8 fp32 into bf16 hi/lo short8 fragments (v_perm packing).
union U8 { short8 s; unsigned int u[4]; };
static __device__ __forceinline__ void split8(floatx4 a0, floatx4 a1,
                                              short8& hi, short8& lo) {
    float f[8] = {a0[0], a0[1], a0[2], a0[3], a1[0], a1[1], a1[2], a1[3]};
    U8 H, L;
#pragma unroll
    for (int j = 0; j < 4; ++j) {
        unsigned u0 = fbits(f[2 * j]);
        unsigned u1 = fbits(f[2 * j + 1]);
        H.u[j] = __builtin_amdgcn_perm(u1, u0, 0x07060302u);
        float r0 = f[2 * j] - bbits(u0 & 0xFFFF0000u);
        float r1 = f[2 * j + 1] - bbits(u1 & 0xFFFF0000u);
        L.u[j] = __builtin_amdgcn_perm(fbits(r1), fbits(r0), 0x07060302u);
    }
    hi = H.s;
    lo = L.s;
}

// ---------------- K1: per-workgroup bucket histogram ----------------
__global__ __launch_bounds__(256) void k1_bucket_hist(const int* __restrict__ dst,
                                                      int* __restrict__ H,
                                                      int E, int chunk, int nbuck) {
    __shared__ int cnt[512];
    for (int i = threadIdx.x; i < nbuck; i += 256) cnt[i] = 0;
    __syncthreads();
    const int g = blockIdx.x;
    const int e0 = g * chunk;
    const int e1 = min(E, e0 + chunk);
    for (int e = e0 + threadIdx.x; e < e1; e += 256)
        atomicAdd(&cnt[dst[e] >> BSHIFT], 1);
    __syncthreads();
    for (int i = threadIdx.x; i < nbuck; i += 256) H[i * NWG + g] = cnt[i];
}

// ---------------- 2-level exclusive scan (over H, bucket-major) ----------------
__global__ __launch_bounds__(1024) void scan_a(const int* __restrict__ in,
                                               int* __restrict__ out,
                                               int* __restrict__ bsums, int n) {
    __shared__ int sm[1024];
    int i = blockIdx.x * 1024 + threadIdx.x;
    int v = (i < n) ? in[i] : 0;
    sm[threadIdx.x] = v;
    __syncthreads();
    for (int off = 1; off < 1024; off <<= 1) {
        int t = (threadIdx.x >= off) ? sm[threadIdx.x - off] : 0;
        __syncthreads();
        sm[threadIdx.x] += t;
        __syncthreads();
    }
    if (i < n) out[i] = sm[threadIdx.x] - v;  // exclusive (pre block offset)
    if (threadIdx.x == 1023) bsums[blockIdx.x] = sm[1023];
}

__global__ __launch_bounds__(1024) void scan_b(const int* __restrict__ bsums,
                                               int* __restrict__ boffs, int NB) {
    __shared__ int sm[1024];
    int v = (threadIdx.x < NB) ? bsums[threadIdx.x] : 0;
    sm[threadIdx.x] = v;
    __syncthreads();
    for (int off = 1; off < 1024; off <<= 1) {
        int t = (threadIdx.x >= off) ? sm[threadIdx.x - off] : 0;
        __syncthreads();
        sm[threadIdx.x] += t;
        __syncthreads();
    }
    if (threadIdx.x < NB) boffs[threadIdx.x] = sm[threadIdx.x] - v;
}

// ---------------- K3: binned append of packed (dstlow8<<17 | src17) ----------------
__global__ __launch_bounds__(256) void k3_bin(const int* __restrict__ src,
                                              const int* __restrict__ dst,
                                              const int* __restrict__ O,
                                              const int* __restrict__ boffs,
                                              int* __restrict__ packed,
                                              int E, int chunk, int nbuck) {
    __shared__ int cur[512];
    const int g = blockIdx.x;
    for (int i = threadIdx.x; i < nbuck; i += 256) {
        const int fi = i * NWG + g;
        cur[i] = O[fi] + boffs[fi >> 10];
    }
    __syncthreads();
    const int e0 = g * chunk;
    const int e1 = min(E, e0 + chunk);
    for (int e = e0 + threadIdx.x; e < e1; e += 256) {
        const int d = dst[e];
        const int b = d >> BSHIFT;
        const int pos = atomicAdd(&cur[b], 1);
        packed[pos] = ((d & (NPB - 1)) << 17) | src[e];
    }
}

// ---------------- K4: within-bucket sort -> rowptr, dinv, col ----------------
__global__ __launch_bounds__(256) void k4_local_sort(const int* __restrict__ O,
                                                     const int* __restrict__ boffs,
                                                     const int* __restrict__ packed,
                                                     int* __restrict__ rowptr,
                                                     float* __restrict__ dinv,
                                                     int* __restrict__ col,
                                                     int N, int E, int nbuck) {
    __shared__ int lcnt[NPB];
    __shared__ int s[NPB];
    __shared__ int lpos[NPB];
    const int b = blockIdx.x;
    const int ib = b * NWG;
    const int segbeg = O[ib] + boffs[ib >> 10];
    int segend = E;
    if (b + 1 < nbuck) {
        const int ie = (b + 1) * NWG;
        segend = O[ie] + boffs[ie >> 10];
    }
    const int n0 = b << BSHIFT;
    const int ncnt = min(N - n0, NPB);
    const int t = threadIdx.x;

    lcnt[t] = 0;
    __syncthreads();
    for (int e = segbeg + t; e < segend; e += 256)
        atomicAdd(&lcnt[packed[e] >> 17], 1);
    __syncthreads();
    // inclusive scan of lcnt into s
    s[t] = lcnt[t];
    __syncthreads();
    for (int off = 1; off < NPB; off <<= 1) {
        int v = (t >= off) ? s[t - off] : 0;
        __syncthreads();
        s[t] += v;
        __syncthreads();
    }
    const int excl = s[t] - lcnt[t];
    lpos[t] = excl;
    if (t < ncnt) {
        rowptr[n0 + t] = segbeg + excl;
        dinv[n0 + t] = rsqrtf((float)(lcnt[t] + 1));  // +1 self-loop
    }
    if (b == nbuck - 1 && t == 0) rowptr[N] = E;
    __syncthreads();
    for (int e = segbeg + t; e < segend; e += 256) {
        const int p = packed[e];
        const int dl = p >> 17;
        const int pos = segbeg + atomicAdd(&lpos[dl], 1);
        col[pos] = p & 0x1FFFF;
    }
}

// ---------------- h2 = bf16((x @ W) * dinv[row])  via bf16x3 MFMA ----------------
// 512 threads = 8 waves; each wave computes 32 rows (two 16-row tiles) x 64 cols.
__global__ __launch_bounds__(512) void gemm_mfma_kernel(const float* __restrict__ x,
                                                        const float* __restrict__ W,
                                                        const float* __restrict__ dinv,
                                                        unsigned short* __restrict__ h2,
                                                        int N) {
    __shared__ unsigned short Whi[COUT * WPAD];
    __shared__ unsigned short Wlo[COUT * WPAD];
    for (int i = threadIdx.x; i < CIN * COUT; i += 512) {
        int k = i >> 6, c = i & 63;
        float w = W[i];
        unsigned u = fbits(w);
        unsigned short h = (unsigned short)(u >> 16);  // trunc split
        float r = w - bbits(u & 0xFFFF0000u);
        Whi[c * WPAD + k] = h;
        Wlo[c * WPAD + k] = (unsigned short)(fbits(r) >> 16);
    }
    __syncthreads();

    const int lane = threadIdx.x & 63;
    const int wave = threadIdx.x >> 6;
    const int m = lane & 15;
    const int q = lane >> 4;
    const int row0 = blockIdx.x * 256 + wave * 32;

    int ar0 = row0 + m;
    int ar1 = row0 + 16 + m;
    if (ar0 >= N) ar0 = N - 1;  // clamp; stores are guarded
    if (ar1 >= N) ar1 = N - 1;
    const float* __restrict__ xr0 = x + (size_t)ar0 * CIN + q * 8;
    const float* __restrict__ xr1 = x + (size_t)ar1 * CIN + q * 8;

    floatx4 acc0[4] = {floatx4{0,0,0,0}, floatx4{0,0,0,0}, floatx4{0,0,0,0}, floatx4{0,0,0,0}};
    floatx4 acc1[4] = {floatx4{0,0,0,0}, floatx4{0,0,0,0}, floatx4{0,0,0,0}, floatx4{0,0,0,0}};

#pragma unroll
    for (int kc = 0; kc < 8; ++kc) {
        floatx4 a00 = *(const floatx4*)(xr0 + kc * 32);
        floatx4 a01 = *(const floatx4*)(xr0 + kc * 32 + 4);
        floatx4 a10 = *(const floatx4*)(xr1 + kc * 32);
        floatx4 a11 = *(const floatx4*)(xr1 + kc * 32 + 4);
        short8 ahi0, alo0, ahi1, alo1;
        split8(a00, a01, ahi0, alo0);
        split8(a10, a11, ahi1, alo1);
        const int kb = kc * 32 + q * 8;
#pragma unroll
        for (int ct = 0; ct < 4; ++ct) {
            const int c = ct * 16 + m;
            short8 bhi = *(const short8*)&Whi[c * WPAD + kb];
            short8 blo = *(const short8*)&Wlo[c * WPAD + kb];
            acc0[ct] = __builtin_amdgcn_mfma_f32_16x16x32_bf16(ahi0, bhi, acc0[ct], 0, 0, 0);
            acc0[ct] = __builtin_amdgcn_mfma_f32_16x16x32_bf16(ahi0, blo, acc0[ct], 0, 0, 0);
            acc0[ct] = __builtin_amdgcn_mfma_f32_16x16x32_bf16(alo0, bhi, acc0[ct], 0, 0, 0);
            acc1[ct] = __builtin_amdgcn_mfma_f32_16x16x32_bf16(ahi1, bhi, acc1[ct], 0, 0, 0);
            acc1[ct] = __builtin_amdgcn_mfma_f32_16x16x32_bf16(ahi1, blo, acc1[ct], 0, 0, 0);
            acc1[ct] = __builtin_amdgcn_mfma_f32_16x16x32_bf16(alo1, bhi, acc1[ct], 0, 0, 0);
        }
    }

    // C/D layout: col = lane&15 (= m), row = q*4 + reg
#pragma unroll
    for (int t = 0; t < 2; ++t) {
#pragma unroll
        for (int r = 0; r < 4; ++r) {
            const int row = row0 + t * 16 + q * 4 + r;
            if (row < N) {
                const float dv = dinv[row];
                unsigned short* __restrict__ op = h2 + (size_t)row * COUT;
#pragma unroll
                for (int ct = 0; ct < 4; ++ct) {
                    float v = (t == 0) ? acc0[ct][r] : acc1[ct][r];
                    op[ct * 16 + m] = f2bf(v * dv);
                }
            }
        }
    }
}

// ---------------- pull-gather: one wave per node, lane = channel PAIR ----------------
// half h = lane>>5 handles edges of parity h; c = lane&31 is the dword (2-channel) idx.
// Two edges in flight per wave instruction; halves combined by shfl_xor(32) at the end.
__global__ __launch_bounds__(256) void gather_kernel(const unsigned short* __restrict__ h2,
                                                     const int* __restrict__ rowptr,
                                                     const int* __restrict__ col,
                                                     const float* __restrict__ dinv,
                                                     const float* __restrict__ b,
                                                     float* __restrict__ out, int N) {
    const int lane = threadIdx.x & 63;
    const int h = lane >> 5;
    const int c = lane & 31;
    const int node = blockIdx.x * 4 + (threadIdx.x >> 6);
    if (node >= N) return;
    const unsigned* __restrict__ h2u = (const unsigned*)h2;
    const int p0 = rowptr[node];
    const int p1 = rowptr[node + 1];
    float a0 = 0.f, a1 = 0.f;
    int p = p0;
    // 8 edges per iteration (4 per half), 4 loads in flight per half-wave
    for (; p + 7 < p1; p += 8) {
        const int e0 = col[p + h],     e1 = col[p + 2 + h];
        const int e2 = col[p + 4 + h], e3 = col[p + 6 + h];
        const unsigned u0 = h2u[(size_t)e0 * 32 + c];
        const unsigned u1 = h2u[(size_t)e1 * 32 + c];
        const unsigned u2 = h2u[(size_t)e2 * 32 + c];
        const unsigned u3 = h2u[(size_t)e3 * 32 + c];
        a0 += (bbits(u0 << 16) + bbits(u1 << 16)) + (bbits(u2 << 16) + bbits(u3 << 16));
        a1 += (bbits(u0 & 0xFFFF0000u) + bbits(u1 & 0xFFFF0000u)) +
              (bbits(u2 & 0xFFFF0000u) + bbits(u3 & 0xFFFF0000u));
    }
    for (; p + 1 < p1; p += 2) {
        const int e = col[p + h];
        const unsigned u = h2u[(size_t)e * 32 + c];
        a0 += bbits(u << 16);
        a1 += bbits(u & 0xFFFF0000u);
    }
    if (p < p1 && h == 0) {  // odd leftover edge: half 0 only
        const unsigned u = h2u[(size_t)col[p] * 32 + c];
        a0 += bbits(u << 16);
        a1 += bbits(u & 0xFFFF0000u);
    }
    // combine edge-parity halves
    a0 += __shfl_xor(a0, 32, 64);
    a1 += __shfl_xor(a1, 32, 64);
    if (h == 0) {
        const unsigned su = h2u[(size_t)node * 32 + c];  // self-loop term
        const float dv = dinv[node];
        const float2 bb = ((const float2*)b)[c];
        float2 o;
        o.x = (a0 + bbits(su << 16)) * dv + bb.x;
        o.y = (a1 + bbits(su & 0xFFFF0000u)) * dv + bb.y;
        ((float2*)out)[(size_t)node * 32 + c] = o;
    }
}

// ---------------- launch ----------------
extern "C" void kernel_launch(void* const* d_in, const int* in_sizes, int n_in,
                              void* d_out, int out_size, void* d_ws, size_t ws_size,
                              hipStream_t stream) {
    const float* x = (const float*)d_in[0];
    const int* ei = (const int*)d_in[1];
    const float* W = (const float*)d_in[2];
    const float* b = (const float*)d_in[3];
    float* out = (float*)d_out;

    const int N = in_sizes[0] / CIN;
    const int E = in_sizes[1] / 2;
    const int* src = ei;
    const int* dst = ei + E;

    const int nbuck = (N + NPB - 1) >> BSHIFT;        // 391
    const int nH = nbuck * NWG;                        // 100096
    const int chunk = (E + NWG - 1) / NWG;             // 12500
    const int NBs = (nH + 1023) / 1024;                // 98

    // workspace layout (256 B aligned chunks)
    auto align_up = [](size_t v) { return (v + 255) & ~(size_t)255; };
    char* ws = (char*)d_ws;
    size_t off = 0;
    int* H = (int*)(ws + off);        off = align_up(off + (size_t)nH * 4);
    int* O = (int*)(ws + off);        off = align_up(off + (size_t)nH * 4);
    int* bsums = (int*)(ws + off);    off = align_up(off + (size_t)NBs * 4);
    int* boffs = (int*)(ws + off);    off = align_up(off + (size_t)NBs * 4);
    int* rowptr = (int*)(ws + off);   off = align_up(off + (size_t)(N + 1) * 4);
    float* dinv = (float*)(ws + off); off = align_up(off + (size_t)N * 4);
    int* packed = (int*)(ws + off);   off = align_up(off + (size_t)E * 4);
    int* col = (int*)(ws + off);      off = align_up(off + (size_t)E * 4);
    unsigned short* h2 = (unsigned short*)(ws + off);
    off = align_up(off + (size_t)N * COUT * 2);
    (void)ws_size;

    // 1. per-workgroup bucket histogram
    k1_bucket_hist<<<NWG, 256, 0, stream>>>(dst, H, E, chunk, nbuck);
    // 2-3. exclusive scan of H (bucket-major, wg-minor) -> private ranges O
    scan_a<<<NBs, 1024, 0, stream>>>(H, O, bsums, nH);
    scan_b<<<1, 1024, 0, stream>>>(bsums, boffs, NBs);
    // 4. binned append of packed edges
    k3_bin<<<NWG, 256, 0, stream>>>(src, dst, O, boffs, packed, E, chunk, nbuck);
    // 5. within-bucket counting sort -> rowptr, dinv, col
    k4_local_sort<<<nbuck, 256, 0, stream>>>(O, boffs, packed, rowptr, dinv, col, N, E, nbuck);
    // 6. projection h2 = bf16((x@W)*dinv) via bf16x3 MFMA, 32 rows/wave
    gemm_mfma_kernel<<<(N + 255) / 256, 512, 0, stream>>>(x, W, dinv, h2, N);
    // 7. pull-gather + bias (dword lanes, edge-parity halves)
    gather_kernel<<<(N + 3) / 4, 256, 0, stream>>>(h2, rowptr, col, dinv, b, out, N);
}